// Round 8
// baseline (170.355 us; speedup 1.0000x reference)
//
#include <hip/hip_runtime.h>

// Problem constants (MultiAttention_61340722921598)
#define BATCH 2
#define SEQ   2048
#define DMODEL 1024
#define NHEADS 16
#define HDIM   64
#define WINDOW 128
#define ROWS  (BATCH * SEQ)          // 4096

typedef __bf16 bf16x8 __attribute__((ext_vector_type(8)));
typedef __bf16 bf16x4 __attribute__((ext_vector_type(4)));
typedef float  f32x4  __attribute__((ext_vector_type(4)));

// async global->LDS, 16B per lane; LDS dest = wave-uniform base + lane*16
__device__ __forceinline__ void async_load16(const __bf16* g, __bf16* l) {
    __builtin_amdgcn_global_load_lds(
        (const __attribute__((address_space(1))) unsigned int*)g,
        (__attribute__((address_space(3))) unsigned int*)l, 16, 0, 0);
}

__device__ __forceinline__ bf16x8 cvt8(float4 a, float4 b) {
    bf16x8 o;
    o[0] = (__bf16)a.x; o[1] = (__bf16)a.y; o[2] = (__bf16)a.z; o[3] = (__bf16)a.w;
    o[4] = (__bf16)b.x; o[5] = (__bf16)b.y; o[6] = (__bf16)b.z; o[7] = (__bf16)b.w;
    return o;
}

// ---------------------------------------------------------------------------
// fp32 -> bf16 conversion of the 4 WEIGHTS only (X is converted on the fly
// inside qkv's A-staging now).  Tail computes the RoPE cos/sin table (exact
// libm sincosf, matching the fp32 reference).
// ---------------------------------------------------------------------------
__global__ __launch_bounds__(256) void convert_w(
    const float* __restrict__ Wq, const float* __restrict__ Wk,
    const float* __restrict__ Wv, const float* __restrict__ Wo,
    __bf16* __restrict__ Wbf, float* __restrict__ ct, float* __restrict__ st)
{
    const int WN8 = DMODEL * DMODEL / 8;   // 131,072 per W (2^17)
    const int TOT = 4 * WN8;               // 524,288
    int idx = blockIdx.x * blockDim.x + threadIdx.x;

    if (idx < TOT) {
        int w = idx >> 17;
        int off = idx & (WN8 - 1);
        const float* Wp = (w == 0) ? Wq : (w == 1) ? Wk : (w == 2) ? Wv : Wo;
        const float* src = Wp + (size_t)off * 8;
        float4 a = *(const float4*)src;
        float4 b = *(const float4*)(src + 4);
        *(bf16x8*)(Wbf + (size_t)idx * 8) = cvt8(a, b);
    } else if (idx < TOT + SEQ * 32) {
        int k = idx - TOT;
        int t = k >> 5, d = k & 31;
        float ang = (float)t * expf(-(float)d * 0.28782313662425572f); // ln(1e4)/32
        float s, c;
        sincosf(ang, &s, &c);
        ct[k] = c; st[k] = s;
    }
}

// XCD-locality swizzle (verified r7/r8): id = bx + GX*by, XCD = id&7
// (round-robin dispatch). Each XCD gets GY/8 y-stripes; z-stride
// GX*GY % 8 == 0 keeps the same (x,y) on the same XCD across z.
template<int GX, int GY>
__device__ __forceinline__ void xcd_swizzle(int& xb, int& yb)
{
    int id = blockIdx.x + GX * blockIdx.y;
    int q  = id & 7;
    int s  = id >> 3;
    xb = s % GX;
    yb = (GY / 8) * q + s / GX;
}

// ---------------------------------------------------------------------------
// QKV projection: round-0 measured-best 128x128 BK=128 structure, with the
// A-operand (X) read as FP32 and converted to bf16 during staging:
//   A-path: 2x float4 global load -> 8 cvt -> ds_write_b128 at the SAME
//           lane*16 LDS dest global_load_lds used (swizzle preserved:
//           ds_write is per-lane, layout unchanged).
//   B-path: unchanged global_load_lds from pre-converted Wbf.
// Numerics identical to the old convert+gload path (same RNE casts).
// XOR chunk swizzle (0 conflicts measured): LDS row r slot s holds global
// chunk s^((r>>1)&3); staging lane -> row lane>>2, slot lane&3, src chunk
// (lane&3)^((lane>>3)&3); read slot 8*((lane>>4)^((frow>>1)&3)).
// Epilogue: RoPE (+0.125 Q scale); pairs (d, d+32) in (acc[i][j],
// acc[i][j+2]), d=j*16+(lane&15).  A/B-frag: elem[row=lane&15]
// [k=(lane>>4)*8+j]; C/D: col=lane&15, row=(lane>>4)*4+reg (verified m89,
// rounds 0-6).
// ---------------------------------------------------------------------------
__global__ __launch_bounds__(256) void gemm_qkv_bf(
    const float* __restrict__ Xf, const __bf16* __restrict__ Wbf,
    __bf16* __restrict__ Qb, __bf16* __restrict__ Kb, __bf16* __restrict__ Vb,
    const float* __restrict__ ct, const float* __restrict__ st)
{
    __shared__ __bf16 As[4][128 * 32];
    __shared__ __bf16 Bs[4][128 * 32];

    const int tid  = threadIdx.x;
    const int lane = tid & 63;
    const int wv   = tid >> 6;
    const int wrow = (wv >> 1) * 64;
    const int wcol = (wv & 1) * 64;

    const int z = blockIdx.z;
    const __bf16* W = Wbf + (size_t)z * (DMODEL * DMODEL);
    __bf16* Cz = (z == 0) ? Qb : (z == 1) ? Kb : Vb;

    int xb, yb;
    xcd_swizzle<8, 32>(xb, yb);
    const int m0 = yb * 128;
    const int n0 = xb * 128;

    // staging map (per 16-row call): lane -> row lane>>2, slot lane&3,
    // source chunk (lane&3)^((lane>>3)&3)
    const int srow = lane >> 2;
    const int schk = (lane & 3) ^ ((lane >> 3) & 3);
    const int arbase = wv * 32;
    const int brbase = wv * 32;

    const float*  gAf0 = Xf + (size_t)(m0 + arbase + srow) * DMODEL + 8 * schk;
    const float*  gAf1 = gAf0 + (size_t)16 * DMODEL;
    const __bf16* gB0  = W + (size_t)(n0 + brbase + srow) * DMODEL + 8 * schk;
    const __bf16* gB1  = gB0 + (size_t)16 * DMODEL;

    // fragment read map
    const int frow = lane & 15;
    const int fsw  = 8 * ((lane >> 4) ^ ((frow >> 1) & 3));

    f32x4 acc[4][4];
#pragma unroll
    for (int i = 0; i < 4; ++i)
#pragma unroll
        for (int j = 0; j < 4; ++j) {
            acc[i][j][0] = 0.f; acc[i][j][1] = 0.f;
            acc[i][j][2] = 0.f; acc[i][j][3] = 0.f;
        }

    for (int k0 = 0; k0 < DMODEL; k0 += 128) {
        __syncthreads();                 // prior iter's LDS reads complete
        // ---- issue all fp32 A loads first (independent; latency overlaps)
        float4 a0[4][2], a1[4][2];
#pragma unroll
        for (int h = 0; h < 4; ++h) {
            const float* p0 = gAf0 + k0 + 32 * h;
            const float* p1 = gAf1 + k0 + 32 * h;
            a0[h][0] = *(const float4*)p0;  a0[h][1] = *(const float4*)(p0 + 4);
            a1[h][0] = *(const float4*)p1;  a1[h][1] = *(const float4*)(p1 + 4);
        }
        // ---- B via async global->LDS (unchanged)
#pragma unroll
        for (int h = 0; h < 4; ++h) {
            async_load16(gB0 + k0 + 32 * h, Bs[h] + brbase * 32);
            async_load16(gB1 + k0 + 32 * h, Bs[h] + (brbase + 16) * 32);
        }
        // ---- convert + write A (same dest layout as global_load_lds:
        //      wave-uniform base + lane*16 bytes = 8 elements)
#pragma unroll
        for (int h = 0; h < 4; ++h) {
            *(bf16x8*)(As[h] + arbase * 32 + lane * 8)        = cvt8(a0[h][0], a0[h][1]);
            *(bf16x8*)(As[h] + (arbase + 16) * 32 + lane * 8) = cvt8(a1[h][0], a1[h][1]);
        }
        __syncthreads();                 // drains vmcnt + lgkm: staging visible

#pragma unroll
        for (int h = 0; h < 4; ++h) {
            bf16x8 afr[4], bfr[4];
#pragma unroll
            for (int i = 0; i < 4; ++i)
                afr[i] = *(const bf16x8*)(As[h] + (wrow + 16 * i + frow) * 32 + fsw);
#pragma unroll
            for (int j = 0; j < 4; ++j)
                bfr[j] = *(const bf16x8*)(Bs[h] + (wcol + 16 * j + frow) * 32 + fsw);
#pragma unroll
            for (int i = 0; i < 4; ++i)
#pragma unroll
                for (int j = 0; j < 4; ++j)
                    acc[i][j] = __builtin_amdgcn_mfma_f32_16x16x32_bf16(
                        afr[i], bfr[j], acc[i][j], 0, 0, 0);
        }
    }

#pragma unroll
    for (int i = 0; i < 4; ++i) {
#pragma unroll
        for (int r = 0; r < 4; ++r) {
            int row = m0 + wrow + i * 16 + (lane >> 4) * 4 + r;
            int t = row & (SEQ - 1);
#pragma unroll
            for (int j = 0; j < 2; ++j) {
                int dd = j * 16 + (lane & 15);
                float c = ct[t * 32 + dd];
                float s = st[t * 32 + dd];
                float v0 = acc[i][j][r], v1 = acc[i][j + 2][r];
                float n0v = v0 * c - v1 * s;
                float n1v = v1 * c + v0 * s;
                if (z == 0) { n0v *= 0.125f; n1v *= 0.125f; }
                if (z <= 1) { acc[i][j][r] = n0v; acc[i][j + 2][r] = n1v; }
            }
#pragma unroll
            for (int j = 0; j < 4; ++j) {
                int col = n0 + wcol + j * 16 + (lane & 15);
                Cz[(size_t)row * DMODEL + col] = (__bf16)acc[i][j][r];
            }
        }
    }
}

// ---------------------------------------------------------------------------
// Round-0 BK=128 2-barrier MFMA GEMM body (verified) — used for out-proj.
// C[m][n] = sum_k A[m][k] * B[n][k]. 4 x 32-halves, XOR chunk swizzle.
// ---------------------------------------------------------------------------
template<int TM, int TN>
__device__ __forceinline__ void gemm_mfma_body(
    const __bf16* __restrict__ A, const __bf16* __restrict__ B,
    void* __restrict__ Cout, const float* __restrict__ bias,
    int mode, int N, int K, int m0, int n0)
{
    constexpr bool SQ = (TN == 128);          // 2x2 wave layout
    constexpr int NI = SQ ? 4 : (TM / 64);    // 16-row i-tiles per wave
    constexpr int NAC = TM / 64;              // A staging calls per wave/half
    constexpr int NBC = TN / 64;              // B staging calls per wave/half
    __shared__ __bf16 As[4][TM * 32];
    __shared__ __bf16 Bs[4][TN * 32];

    const int tid  = threadIdx.x;
    const int lane = tid & 63;
    const int wv   = tid >> 6;
    const int wrow = SQ ? (wv >> 1) * 64 : wv * (TM / 4);
    const int wcol = SQ ? (wv & 1) * 64 : 0;

    const int srow = lane >> 2;
    const int schk = (lane & 3) ^ ((lane >> 3) & 3);
    const int arbase = wv * (TM / 4);
    const int brbase = wv * (TN / 4);

    const __bf16* gA0 = A + (size_t)(m0 + arbase + srow) * K + 8 * schk;
    const __bf16* gA1 = gA0 + (size_t)16 * K;
    const __bf16* gB0 = B + (size_t)(n0 + brbase + srow) * K + 8 * schk;
    const __bf16* gB1 = gB0 + (size_t)16 * K;

    const int frow = lane & 15;
    const int fsw  = 8 * ((lane >> 4) ^ ((frow >> 1) & 3));

    f32x4 acc[NI][4];
#pragma unroll
    for (int i = 0; i < NI; ++i)
#pragma unroll
        for (int j = 0; j < 4; ++j) {
            acc[i][j][0] = 0.f; acc[i][j][1] = 0.f;
            acc[i][j][2] = 0.f; acc[i][j][3] = 0.f;
        }

    for (int k0 = 0; k0 < K; k0 += 128) {
        __syncthreads();                 // prior iter's LDS reads complete
#pragma unroll
        for (int h = 0; h < 4; ++h) {
            async_load16(gA0 + k0 + 32 * h, As[h] + arbase * 32);
            if (NAC == 2)
                async_load16(gA1 + k0 + 32 * h, As[h] + (arbase + 16) * 32);
            async_load16(gB0 + k0 + 32 * h, Bs[h] + brbase * 32);
            if (NBC == 2)
                async_load16(gB1 + k0 + 32 * h, Bs[h] + (brbase + 16) * 32);
        }
        __syncthreads();                 // drains vmcnt: staging visible

#pragma unroll
        for (int h = 0; h < 4; ++h) {
            bf16x8 afr[NI], bfr[4];
#pragma unroll
            for (int i = 0; i < NI; ++i)
                afr[i] = *(const bf16x8*)(As[h] + (wrow + 16 * i + frow) * 32 + fsw);
#pragma unroll
            for (int j = 0; j < 4; ++j)
                bfr[j] = *(const bf16x8*)(Bs[h] + (wcol + 16 * j + frow) * 32 + fsw);
#pragma unroll
            for (int i = 0; i < NI; ++i)
#pragma unroll
                for (int j = 0; j < 4; ++j)
                    acc[i][j] = __builtin_amdgcn_mfma_f32_16x16x32_bf16(
                        afr[i], bfr[j], acc[i][j], 0, 0, 0);
        }
    }

#pragma unroll
    for (int i = 0; i < NI; ++i) {
#pragma unroll
        for (int r = 0; r < 4; ++r) {
            int row = m0 + wrow + i * 16 + (lane >> 4) * 4 + r;
#pragma unroll
            for (int j = 0; j < 4; ++j) {
                int col = n0 + wcol + j * 16 + (lane & 15);
                float v = acc[i][j][r];
                if (mode == 3)
                    ((float*)Cout)[(size_t)row * N + col] = v + bias[col];
                else
                    ((__bf16*)Cout)[(size_t)row * N + col] = (__bf16)v;
            }
        }
    }
}

__global__ __launch_bounds__(256) void gemm_out_bf(
    const __bf16* __restrict__ Abf, const __bf16* __restrict__ Wo,
    const float* __restrict__ bias, float* __restrict__ out)
{
    int xb, yb;
    xcd_swizzle<16, 64>(xb, yb);
    gemm_mfma_body<64, 64>(Abf, Wo, out, bias, 3, DMODEL, DMODEL,
                           yb * 64, xb * 64);
}

// ---------------------------------------------------------------------------
// MFMA sliding-window attention (round-5 measured-best: 53248 B LDS -> 3/CU,
// VPAD=200 + clamp, setprio).  One 256-thread block per (b, h, 64 q-rows).
// ---------------------------------------------------------------------------
#define QTILE 64
#define KPAD  72    // Ks row (bf16): 36 words/row -> 8 distinct bank offsets
#define VPAD  200   // Vt row: 100 words -> 8 distinct bank offsets (2-way)
#define PPAD  168   // Ps row: 84 words -> 8 distinct offsets

__global__ __launch_bounds__(256, 3) void attn_mfma(
    const __bf16* __restrict__ Qb, const __bf16* __restrict__ Kb,
    const __bf16* __restrict__ Vb, __bf16* __restrict__ Abf)
{
    __shared__ __bf16 KsPs[192 * KPAD];  // 27648 B; Ks, then reused as Ps
    __shared__ __bf16 Vt[64 * VPAD];     // 25600 B  (total 53248 B -> 3/CU)

    const int tid  = threadIdx.x;
    const int lane = tid & 63;
    const int wv   = tid >> 6;
    const int q0   = blockIdx.x * QTILE;
    const int h    = blockIdx.y;
    const int b    = blockIdx.z;
    const int jbase = q0 - 128;
    const size_t hoff = (size_t)h * HDIM;
    const int nloc  = lane & 15;
    const int mbase = (lane >> 4) * 4;
    const int fk    = (lane >> 4) * 8;

    const __bf16* Kg = Kb + (size_t)(b * SEQ) * DMODEL + hoff;
    const __bf16* Vg = Vb + (size_t)(b * SEQ) * DMODEL + hoff;

    // ---- stage Ks (natural) + Vt (transposed)
#pragma unroll
    for (int it = 0; it < 6; ++it) {
        int idx = tid + it * 256;          // 0..1535
        int jt = idx >> 3;                 // 0..191
        int dq = (idx & 7) * 8;
        int jg = jbase + jt;
        int jc = jg < 0 ? 0 : jg;          // clamp; masked via p=0 later
        bf16x8 kv = *(const bf16x8*)(Kg + (size_t)jc * DMODEL + dq);
        bf16x8 vv = *(const bf16x8*)(Vg + (size_t)jc * DMODEL + dq);
        *(bf16x8*)(KsPs + jt * KPAD + dq) = kv;
#pragma unroll
        for (int e = 0; e < 8; ++e) Vt[(dq + e) * VPAD + jt] = vv[e];
    }
    __syncthreads();

    // ---- Q A-frags direct from global
    const __bf16* Qg = Qb + (size_t)(b * SEQ + q0 + 16 * wv + nloc) * DMODEL + hoff + fk;
    bf16x8 qfr0 = *(const bf16x8*)(Qg);
    bf16x8 qfr1 = *(const bf16x8*)(Qg + 32);

    // ---- S = Q K^T over 9 column tiles
    f32x4 s[9];
    __builtin_amdgcn_s_setprio(1);
#pragma unroll
    for (int c = 0; c < 9; ++c) {
        const __bf16* kp = KsPs + (size_t)(16 * (wv + c) + nloc) * KPAD + fk;
        bf16x8 k0 = *(const bf16x8*)kp;
        bf16x8 k1 = *(const bf16x8*)(kp + 32);
        f32x4 z; z[0] = 0.f; z[1] = 0.f; z[2] = 0.f; z[3] = 0.f;
        z = __builtin_amdgcn_mfma_f32_16x16x32_bf16(qfr0, k0, z, 0, 0, 0);
        z = __builtin_amdgcn_mfma_f32_16x16x32_bf16(qfr1, k1, z, 0, 0, 0);
        s[c] = z;
    }
    __builtin_amdgcn_s_setprio(0);
    __syncthreads();   // all waves done reading Ks; safe to alias with Ps

    // ---- mask + softmax (registers only); write normalized P (bf16)
    float inv_row[4];
#pragma unroll
    for (int r = 0; r < 4; ++r) {
        int rl = 16 * wv + mbase + r;
        float mx = -INFINITY;
#pragma unroll
        for (int c = 0; c < 9; ++c) {
            int jt = 16 * (wv + c) + nloc;
            bool valid = (jt >= rl + 1) && (jt <= rl + 128) && (jbase + jt >= 0);
            float sv = valid ? s[c][r] : -INFINITY;
            s[c][r] = sv;
            mx = fmaxf(mx, sv);
        }
#pragma unroll
        for (int off = 8; off; off >>= 1) mx = fmaxf(mx, __shfl_xor(mx, off));
        float sum = 0.f;
#pragma unroll
        for (int c = 0; c < 9; ++c) {
            float p = __expf(s[c][r] - mx);
            s[c][r] = p;
            sum += p;
        }
#pragma unroll
        for (int off = 8; off; off >>= 1) sum += __shfl_xor(sum, off);
        inv_row[r] = 1.0f / sum;
    }

    __bf16* myP = KsPs + (size_t)wv * 16 * PPAD;
#pragma unroll
    for (int c = 0; c < 9; ++c)
#pragma unroll
        for (int r = 0; r < 4; ++r)
            myP[(mbase + r) * PPAD + 16 * c + nloc] = (__bf16)(s[c][r] * inv_row[r]);
#pragma unroll
    for (int r = 0; r < 4; ++r)       // zero P cols [144,160)
        myP[(mbase + r) * PPAD + 144 + nloc] = (__bf16)0.0f;

    asm volatile("" ::: "memory");
    __builtin_amdgcn_s_waitcnt(0);    // wave-local LDS write->read ordering

    // ---- O = P V  (5 k-steps of 32 keys, 4 d-tiles)
    f32x4 o[4];
#pragma unroll
    for (int j = 0; j < 4; ++j) { o[j][0] = 0.f; o[j][1] = 0.f; o[j][2] = 0.f; o[j][3] = 0.f; }
    __builtin_amdgcn_s_setprio(1);
#pragma unroll
    for (int stp = 0; stp < 5; ++stp) {
        bf16x8 pf = *(const bf16x8*)(myP + nloc * PPAD + 32 * stp + fk);
        int vcol = 16 * wv + 32 * stp + fk;
        if (vcol >= 192) vcol = 0;        // P cols 144..159 are zero; stay in-bounds
#pragma unroll
        for (int j = 0; j < 4; ++j) {
            bf16x8 vf = *(const bf16x8*)(Vt + (size_t)(16 * j + nloc) * VPAD + vcol);
            o[j] = __builtin_amdgcn_mfma_f32_16x16x32_bf16(pf, vf, o[j], 0, 0, 0);
        }
    }
    __builtin_amdgcn_s_setprio(0);

    // ---- epilogue: C-layout -> global bf16
    __bf16* Og = Abf + (size_t)(b * SEQ + q0 + 16 * wv) * DMODEL + hoff;
#pragma unroll
    for (int j = 0; j < 4; ++j)
#pragma unroll
        for (int r = 0; r < 4; ++r)
            Og[(size_t)(mbase + r) * DMODEL + 16 * j + nloc] = (__bf16)o[j][r];
}

// ---------------------------------------------------------------------------
extern "C" void kernel_launch(void* const* d_in, const int* in_sizes, int n_in,
                              void* d_out, int out_size, void* d_ws, size_t ws_size,
                              hipStream_t stream)
{
    const float* X  = (const float*)d_in[0];
    const float* Wq = (const float*)d_in[1];
    const float* Wk = (const float*)d_in[2];
    const float* Wv = (const float*)d_in[3];
    const float* Wo = (const float*)d_in[4];
    const float* bo = (const float*)d_in[5];
    float* out = (float*)d_out;

    const size_t MB = 1ull << 20;
    __bf16* Abf = (__bf16*)d_ws;                        // 8 MB (attn output)
    __bf16* Wbf = (__bf16*)((char*)d_ws + 8 * MB);      // 8 MB (Wq|Wk|Wv|Wo)
    __bf16* Qb  = (__bf16*)((char*)d_ws + 16 * MB);     // 8 MB
    __bf16* Kb  = (__bf16*)((char*)d_ws + 24 * MB);     // 8 MB
    __bf16* Vb  = (__bf16*)((char*)d_ws + 32 * MB);     // 8 MB
    float*  ctab = (float*)((char*)d_ws + 40 * MB);     // 256 KB
    float*  stab = (float*)((char*)d_ws + 41 * MB);     // 256 KB

    // 1. weight fp32 -> bf16 conversion + RoPE table (X converted in qkv)
    {
        int total = (4 * DMODEL * DMODEL) / 8 + SEQ * 32;
        convert_w<<<(total + 255) / 256, 256, 0, stream>>>(
            Wq, Wk, Wv, Wo, Wbf, ctab, stab);
    }
    // 2. QKV projections (A = X fp32, converted during staging), fused RoPE
    {
        dim3 grid(DMODEL / 128, ROWS / 128, 3);
        gemm_qkv_bf<<<grid, 256, 0, stream>>>(X, Wbf, Qb, Kb, Vb, ctab, stab);
    }
    // 3. MFMA sliding-window attention -> bf16 (round-5 verified config)
    {
        dim3 grid(SEQ / QTILE, NHEADS, BATCH);
        attn_mfma<<<grid, 256, 0, stream>>>(Qb, Kb, Vb, Abf);
    }
    // 4. Output projection + bias (fp32 out); 64x64 tiles (round-0 verified)
    {
        dim3 grid(DMODEL / 64, ROWS / 64, 1);
        gemm_out_bf<<<grid, 256, 0, stream>>>(Abf, Wbf + 3ull * DMODEL * DMODEL, bo, out);
    }
}

// Round 9
// 160.329 us; speedup vs baseline: 1.0625x; 1.0625x over previous
//
#include <hip/hip_runtime.h>

// Problem constants (MultiAttention_61340722921598)
#define BATCH 2
#define SEQ   2048
#define DMODEL 1024
#define NHEADS 16
#define HDIM   64
#define WINDOW 128
#define ROWS  (BATCH * SEQ)          // 4096

typedef __bf16 bf16x8 __attribute__((ext_vector_type(8)));
typedef __bf16 bf16x4 __attribute__((ext_vector_type(4)));
typedef float  f32x4  __attribute__((ext_vector_type(4)));

// async global->LDS, 16B per lane; LDS dest = wave-uniform base + lane*16
__device__ __forceinline__ void async_load16(const __bf16* g, __bf16* l) {
    __builtin_amdgcn_global_load_lds(
        (const __attribute__((address_space(1))) unsigned int*)g,
        (__attribute__((address_space(3))) unsigned int*)l, 16, 0, 0);
}

// ---------------------------------------------------------------------------
// fp32 -> bf16 conversion, 8 floats/thread.  Tail range computes the RoPE
// cos/sin table (exact libm sincosf, matching the fp32 reference).
// ---------------------------------------------------------------------------
__global__ __launch_bounds__(256) void convert_bf16(
    const float* __restrict__ X,
    const float* __restrict__ Wq, const float* __restrict__ Wk,
    const float* __restrict__ Wv, const float* __restrict__ Wo,
    __bf16* __restrict__ Xbf, __bf16* __restrict__ Wbf,
    float* __restrict__ ct, float* __restrict__ st)
{
    const int XN8 = ROWS * DMODEL / 8;     // 524,288 groups of 8
    const int WN8 = DMODEL * DMODEL / 8;   // 131,072 per W (2^17)
    const int TOT = XN8 + 4 * WN8;         // 1,048,576
    int idx = blockIdx.x * blockDim.x + threadIdx.x;

    if (idx < TOT) {
        const float* src;
        __bf16* dst;
        if (idx < XN8) {
            src = X + (size_t)idx * 8;
            dst = Xbf + (size_t)idx * 8;
        } else {
            int rel = idx - XN8;
            int w = rel >> 17;
            int off = rel & (WN8 - 1);
            const float* Wp = (w == 0) ? Wq : (w == 1) ? Wk : (w == 2) ? Wv : Wo;
            src = Wp + (size_t)off * 8;
            dst = Wbf + (size_t)rel * 8;
        }
        float4 a = *(const float4*)src;
        float4 b = *(const float4*)(src + 4);
        bf16x8 o;
        o[0] = (__bf16)a.x; o[1] = (__bf16)a.y; o[2] = (__bf16)a.z; o[3] = (__bf16)a.w;
        o[4] = (__bf16)b.x; o[5] = (__bf16)b.y; o[6] = (__bf16)b.z; o[7] = (__bf16)b.w;
        *(bf16x8*)dst = o;
    } else if (idx < TOT + SEQ * 32) {
        int k = idx - TOT;
        int t = k >> 5, d = k & 31;
        float ang = (float)t * expf(-(float)d * 0.28782313662425572f); // ln(1e4)/32
        float s, c;
        sincosf(ang, &s, &c);
        ct[k] = c; st[k] = s;
    }
}

// ---------------------------------------------------------------------------
// bf16 MFMA GEMM (round-0 measured-best): C[m][n] = sum_k A[m][k] * B[n][k].
// BK=128 (4 x 32-halves, XOR chunk swizzle: LDS row r slot s holds global
// chunk s^((r>>1)&3) via source-address permutation; 0 conflicts measured).
// 256 threads = 4 waves.
//   TN=128 -> 2x2 wave layout: wave = 64x64 outputs, 8 ds_read_b128 per
//             16 MFMA (0.5/MFMA, m97 ratio). LDS 64 KB, 2 blocks/CU.
//   TN=64  -> 4x1 wave layout (used for out-proj).
// Epilogue modes: 0=Q (RoPE+0.125, bf16), 1=K (RoPE, bf16), 2=V (bf16),
// 3=fp32+bias. wcol is a multiple of 64 in both layouts -> RoPE pairs
// (d, d+32) stay in one wave as (acc[i][j], acc[i][j+2]), d=j*16+(lane&15).
// A/B-frag: elem[row=lane&15][k=(lane>>4)*8+j]; C/D: col=lane&15,
// row=(lane>>4)*4+reg (verified m89, rounds 0-8).
// ---------------------------------------------------------------------------
template<int TM, int TN>
__device__ __forceinline__ void gemm_mfma_body(
    const __bf16* __restrict__ A, const __bf16* __restrict__ B,
    void* __restrict__ Cout, const float* __restrict__ bias,
    const float* __restrict__ ct, const float* __restrict__ st,
    int mode, int N, int K, int m0, int n0)
{
    constexpr bool SQ = (TN == 128);          // 2x2 wave layout
    constexpr int NI = SQ ? 4 : (TM / 64);    // 16-row i-tiles per wave
    constexpr int NAC = TM / 64;              // A staging calls per wave/half
    constexpr int NBC = TN / 64;              // B staging calls per wave/half
    __shared__ __bf16 As[4][TM * 32];
    __shared__ __bf16 Bs[4][TN * 32];

    const int tid  = threadIdx.x;
    const int lane = tid & 63;
    const int wv   = tid >> 6;
    const int wrow = SQ ? (wv >> 1) * 64 : wv * (TM / 4);
    const int wcol = SQ ? (wv & 1) * 64 : 0;

    // staging map (per 16-row call): lane -> row lane>>2, slot lane&3,
    // source chunk (lane&3)^((lane>>3)&3); row-base-invariant (base % 16 == 0)
    const int srow = lane >> 2;
    const int schk = (lane & 3) ^ ((lane >> 3) & 3);
    const int arbase = wv * (TM / 4);
    const int brbase = wv * (TN / 4);

    const __bf16* gA0 = A + (size_t)(m0 + arbase + srow) * K + 8 * schk;
    const __bf16* gA1 = gA0 + (size_t)16 * K;
    const __bf16* gB0 = B + (size_t)(n0 + brbase + srow) * K + 8 * schk;
    const __bf16* gB1 = gB0 + (size_t)16 * K;

    // fragment read map: row frow, global chunk lane>>4 at swizzled slot
    const int frow = lane & 15;
    const int fsw  = 8 * ((lane >> 4) ^ ((frow >> 1) & 3));

    f32x4 acc[NI][4];
#pragma unroll
    for (int i = 0; i < NI; ++i)
#pragma unroll
        for (int j = 0; j < 4; ++j) {
            acc[i][j][0] = 0.f; acc[i][j][1] = 0.f;
            acc[i][j][2] = 0.f; acc[i][j][3] = 0.f;
        }

    for (int k0 = 0; k0 < K; k0 += 128) {
        __syncthreads();                 // prior iter's LDS reads complete
#pragma unroll
        for (int h = 0; h < 4; ++h) {
            async_load16(gA0 + k0 + 32 * h, As[h] + arbase * 32);
            if (NAC == 2)
                async_load16(gA1 + k0 + 32 * h, As[h] + (arbase + 16) * 32);
            async_load16(gB0 + k0 + 32 * h, Bs[h] + brbase * 32);
            if (NBC == 2)
                async_load16(gB1 + k0 + 32 * h, Bs[h] + (brbase + 16) * 32);
        }
        __syncthreads();                 // drains vmcnt: staging visible

#pragma unroll
        for (int h = 0; h < 4; ++h) {
            bf16x8 afr[NI], bfr[4];
#pragma unroll
            for (int i = 0; i < NI; ++i)
                afr[i] = *(const bf16x8*)(As[h] + (wrow + 16 * i + frow) * 32 + fsw);
#pragma unroll
            for (int j = 0; j < 4; ++j)
                bfr[j] = *(const bf16x8*)(Bs[h] + (wcol + 16 * j + frow) * 32 + fsw);
#pragma unroll
            for (int i = 0; i < NI; ++i)
#pragma unroll
                for (int j = 0; j < 4; ++j)
                    acc[i][j] = __builtin_amdgcn_mfma_f32_16x16x32_bf16(
                        afr[i], bfr[j], acc[i][j], 0, 0, 0);
        }
    }

#pragma unroll
    for (int i = 0; i < NI; ++i) {
#pragma unroll
        for (int r = 0; r < 4; ++r) {
            int row = m0 + wrow + i * 16 + (lane >> 4) * 4 + r;
            if (mode <= 1) {
                // RoPE: pairs (d, d+32) in (acc[i][j], acc[i][j+2]), d=j*16+(lane&15)<32
                int t = row & (SEQ - 1);
#pragma unroll
                for (int j = 0; j < 2; ++j) {
                    int dd = j * 16 + (lane & 15);
                    float c = ct[t * 32 + dd];
                    float s = st[t * 32 + dd];
                    float v0 = acc[i][j][r], v1 = acc[i][j + 2][r];
                    float n0v = v0 * c - v1 * s;
                    float n1v = v1 * c + v0 * s;
                    if (mode == 0) { n0v *= 0.125f; n1v *= 0.125f; }
                    acc[i][j][r] = n0v; acc[i][j + 2][r] = n1v;
                }
            }
#pragma unroll
            for (int j = 0; j < 4; ++j) {
                int col = n0 + wcol + j * 16 + (lane & 15);
                float v = acc[i][j][r];
                if (mode == 3)
                    ((float*)Cout)[(size_t)row * N + col] = v + bias[col];
                else
                    ((__bf16*)Cout)[(size_t)row * N + col] = (__bf16)v;
            }
        }
    }
}

// XCD-locality swizzle (verified r7/r8): id = bx + GX*by, XCD = id&7
// (round-robin dispatch). Each XCD gets GY/8 y-stripes so the GX blocks
// sharing one A-row-tile sit on ONE XCD; z-stride GX*GY % 8 == 0 keeps the
// same (x,y) on the same XCD across z.
template<int GX, int GY>
__device__ __forceinline__ void xcd_swizzle(int& xb, int& yb)
{
    int id = blockIdx.x + GX * blockIdx.y;
    int q  = id & 7;
    int s  = id >> 3;
    xb = s % GX;
    yb = (GY / 8) * q + s / GX;
}

__global__ __launch_bounds__(256) void gemm_qkv_bf(
    const __bf16* __restrict__ X, const __bf16* __restrict__ Wbf,
    __bf16* __restrict__ Qb, __bf16* __restrict__ Kb, __bf16* __restrict__ Vb,
    const float* __restrict__ ct, const float* __restrict__ st)
{
    const int z = blockIdx.z;
    const __bf16* W = Wbf + (size_t)z * (DMODEL * DMODEL);
    __bf16* C = (z == 0) ? Qb : (z == 1) ? Kb : Vb;
    int xb, yb;
    xcd_swizzle<8, 32>(xb, yb);
    gemm_mfma_body<128, 128>(X, W, C, nullptr, ct, st, z, DMODEL, DMODEL,
                             yb * 128, xb * 128);
}

__global__ __launch_bounds__(256) void gemm_out_bf(
    const __bf16* __restrict__ Abf, const __bf16* __restrict__ Wo,
    const float* __restrict__ bias, float* __restrict__ out)
{
    int xb, yb;
    xcd_swizzle<16, 64>(xb, yb);
    gemm_mfma_body<64, 64>(Abf, Wo, out, bias, nullptr, nullptr, 3,
                           DMODEL, DMODEL, yb * 64, xb * 64);
}

// ---------------------------------------------------------------------------
// MFMA sliding-window attention (round-5 config + Vt store swizzle).
// One 256-thread block per (b, h, 64 q-rows); wave w owns q-rows 16w..16w+15.
// Round-9 change: the Vt transpose-store was a 16-way bank conflict —
// store bank = (800k + 100e + jt/2) mod 32 with 800k ≡ 0 (mod 32), so all
// 64 lanes hit 4 banks on 48 scalar ds_write_b16/thread.  Fix: XOR the
// column with the lane's row-chunk (8*((row>>3)&7) == dq, a per-thread
// constant): store col' = jt ^ dq -> banks (4e + 4*((J0/8)^k) + lj/2),
// all 32 banks, 2 lanes each (free).  Chunk-XOR keeps col' in [0,192) and
// preserves b128 read contiguity; reads apply the same same-row involution
// vc = vcol ^ 8*((2j + (nloc>>3))&7) (read-bank pattern unchanged from the
// verified round-5 layout).  Clamp case still reads true col 0 (P = 0).
// ---------------------------------------------------------------------------
#define QTILE 64
#define KPAD  72    // Ks row (bf16): 36 words/row -> 8 distinct bank offsets
#define VPAD  200   // Vt row: 100 words
#define PPAD  168   // Ps row: 84 words -> 8 distinct offsets

__global__ __launch_bounds__(256, 3) void attn_mfma(
    const __bf16* __restrict__ Qb, const __bf16* __restrict__ Kb,
    const __bf16* __restrict__ Vb, __bf16* __restrict__ Abf)
{
    __shared__ __bf16 KsPs[192 * KPAD];  // 27648 B; Ks, then reused as Ps
    __shared__ __bf16 Vt[64 * VPAD];     // 25600 B  (total 53248 B -> 3/CU)

    const int tid  = threadIdx.x;
    const int lane = tid & 63;
    const int wv   = tid >> 6;
    const int q0   = blockIdx.x * QTILE;
    const int h    = blockIdx.y;
    const int b    = blockIdx.z;
    const int jbase = q0 - 128;
    const size_t hoff = (size_t)h * HDIM;
    const int nloc  = lane & 15;
    const int mbase = (lane >> 4) * 4;
    const int fk    = (lane >> 4) * 8;

    const __bf16* Kg = Kb + (size_t)(b * SEQ) * DMODEL + hoff;
    const __bf16* Vg = Vb + (size_t)(b * SEQ) * DMODEL + hoff;

    // ---- stage Ks (natural) + Vt (transposed, column-XOR-swizzled)
#pragma unroll
    for (int it = 0; it < 6; ++it) {
        int idx = tid + it * 256;          // 0..1535
        int jt = idx >> 3;                 // 0..191
        int dq = (idx & 7) * 8;            // row-chunk base; also the XOR const
        int jg = jbase + jt;
        int jc = jg < 0 ? 0 : jg;          // clamp; masked via p=0 later
        bf16x8 kv = *(const bf16x8*)(Kg + (size_t)jc * DMODEL + dq);
        bf16x8 vv = *(const bf16x8*)(Vg + (size_t)jc * DMODEL + dq);
        *(bf16x8*)(KsPs + jt * KPAD + dq) = kv;
        const int jsw = jt ^ dq;           // col' = col ^ (8*((row>>3)&7))
#pragma unroll
        for (int e = 0; e < 8; ++e) Vt[(dq + e) * VPAD + jsw] = vv[e];
    }
    __syncthreads();

    // ---- Q A-frags direct from global
    const __bf16* Qg = Qb + (size_t)(b * SEQ + q0 + 16 * wv + nloc) * DMODEL + hoff + fk;
    bf16x8 qfr0 = *(const bf16x8*)(Qg);
    bf16x8 qfr1 = *(const bf16x8*)(Qg + 32);

    // ---- S = Q K^T over 9 column tiles
    f32x4 s[9];
    __builtin_amdgcn_s_setprio(1);
#pragma unroll
    for (int c = 0; c < 9; ++c) {
        const __bf16* kp = KsPs + (size_t)(16 * (wv + c) + nloc) * KPAD + fk;
        bf16x8 k0 = *(const bf16x8*)kp;
        bf16x8 k1 = *(const bf16x8*)(kp + 32);
        f32x4 z; z[0] = 0.f; z[1] = 0.f; z[2] = 0.f; z[3] = 0.f;
        z = __builtin_amdgcn_mfma_f32_16x16x32_bf16(qfr0, k0, z, 0, 0, 0);
        z = __builtin_amdgcn_mfma_f32_16x16x32_bf16(qfr1, k1, z, 0, 0, 0);
        s[c] = z;
    }
    __builtin_amdgcn_s_setprio(0);
    __syncthreads();   // all waves done reading Ks; safe to alias with Ps

    // ---- mask + softmax (registers only); write normalized P (bf16)
    float inv_row[4];
#pragma unroll
    for (int r = 0; r < 4; ++r) {
        int rl = 16 * wv + mbase + r;
        float mx = -INFINITY;
#pragma unroll
        for (int c = 0; c < 9; ++c) {
            int jt = 16 * (wv + c) + nloc;
            bool valid = (jt >= rl + 1) && (jt <= rl + 128) && (jbase + jt >= 0);
            float sv = valid ? s[c][r] : -INFINITY;
            s[c][r] = sv;
            mx = fmaxf(mx, sv);
        }
#pragma unroll
        for (int off = 8; off; off >>= 1) mx = fmaxf(mx, __shfl_xor(mx, off));
        float sum = 0.f;
#pragma unroll
        for (int c = 0; c < 9; ++c) {
            float p = __expf(s[c][r] - mx);
            s[c][r] = p;
            sum += p;
        }
#pragma unroll
        for (int off = 8; off; off >>= 1) sum += __shfl_xor(sum, off);
        inv_row[r] = 1.0f / sum;
    }

    __bf16* myP = KsPs + (size_t)wv * 16 * PPAD;
#pragma unroll
    for (int c = 0; c < 9; ++c)
#pragma unroll
        for (int r = 0; r < 4; ++r)
            myP[(mbase + r) * PPAD + 16 * c + nloc] = (__bf16)(s[c][r] * inv_row[r]);
#pragma unroll
    for (int r = 0; r < 4; ++r)       // zero P cols [144,160)
        myP[(mbase + r) * PPAD + 144 + nloc] = (__bf16)0.0f;

    asm volatile("" ::: "memory");
    __builtin_amdgcn_s_waitcnt(0);    // wave-local LDS write->read ordering

    // ---- O = P V  (5 k-steps of 32 keys, 4 d-tiles)
    f32x4 o[4];
#pragma unroll
    for (int j = 0; j < 4; ++j) { o[j][0] = 0.f; o[j][1] = 0.f; o[j][2] = 0.f; o[j][3] = 0.f; }
    __builtin_amdgcn_s_setprio(1);
#pragma unroll
    for (int stp = 0; stp < 5; ++stp) {
        bf16x8 pf = *(const bf16x8*)(myP + nloc * PPAD + 32 * stp + fk);
        int vcol = 16 * wv + 32 * stp + fk;
        if (vcol >= 192) vcol = 0;        // P cols 144..159 are zero; stay in-bounds
#pragma unroll
        for (int j = 0; j < 4; ++j) {
            int row = 16 * j + nloc;
            int vc  = vcol ^ (8 * ((2 * j + (nloc >> 3)) & 7));  // same-row inverse
            bf16x8 vf = *(const bf16x8*)(Vt + (size_t)row * VPAD + vc);
            o[j] = __builtin_amdgcn_mfma_f32_16x16x32_bf16(pf, vf, o[j], 0, 0, 0);
        }
    }
    __builtin_amdgcn_s_setprio(0);

    // ---- epilogue: C-layout -> global bf16
    __bf16* Og = Abf + (size_t)(b * SEQ + q0 + 16 * wv) * DMODEL + hoff;
#pragma unroll
    for (int j = 0; j < 4; ++j)
#pragma unroll
        for (int r = 0; r < 4; ++r)
            Og[(size_t)(mbase + r) * DMODEL + 16 * j + nloc] = (__bf16)o[j][r];
}

// ---------------------------------------------------------------------------
extern "C" void kernel_launch(void* const* d_in, const int* in_sizes, int n_in,
                              void* d_out, int out_size, void* d_ws, size_t ws_size,
                              hipStream_t stream)
{
    const float* X  = (const float*)d_in[0];
    const float* Wq = (const float*)d_in[1];
    const float* Wk = (const float*)d_in[2];
    const float* Wv = (const float*)d_in[3];
    const float* Wo = (const float*)d_in[4];
    const float* bo = (const float*)d_in[5];
    float* out = (float*)d_out;

    const size_t MB = 1ull << 20;
    __bf16* Xbf = (__bf16*)d_ws;                        // 8 MB; reused as Abf
    __bf16* Wbf = (__bf16*)((char*)d_ws + 8 * MB);      // 8 MB (Wq|Wk|Wv|Wo)
    __bf16* Qb  = (__bf16*)((char*)d_ws + 16 * MB);     // 8 MB
    __bf16* Kb  = (__bf16*)((char*)d_ws + 24 * MB);     // 8 MB
    __bf16* Vb  = (__bf16*)((char*)d_ws + 32 * MB);     // 8 MB
    float*  ctab = (float*)((char*)d_ws + 40 * MB);     // 256 KB
    float*  stab = (float*)((char*)d_ws + 41 * MB);     // 256 KB
    __bf16* Abf = Xbf;   // X dead after QKV projection

    // 1. fp32 -> bf16 conversion + RoPE table (fused); 8 floats/thread
    {
        int total = (ROWS * DMODEL + 4 * DMODEL * DMODEL) / 8 + SEQ * 32;
        convert_bf16<<<(total + 255) / 256, 256, 0, stream>>>(
            X, Wq, Wk, Wv, Wo, Xbf, Wbf, ctab, stab);
    }
    // 2. QKV projections with fused RoPE (+Q scale), bf16 out; 128x128 tiles
    //    (round-0 measured-best config)
    {
        dim3 grid(DMODEL / 128, ROWS / 128, 3);
        gemm_qkv_bf<<<grid, 256, 0, stream>>>(Xbf, Wbf, Qb, Kb, Vb, ctab, stab);
    }
    // 3. MFMA sliding-window attention -> bf16 (Vt store-swizzle fix)
    {
        dim3 grid(SEQ / QTILE, NHEADS, BATCH);
        attn_mfma<<<grid, 256, 0, stream>>>(Qb, Kb, Vb, Abf);
    }
    // 4. Output projection + bias (fp32 out); 64x64 tiles (round-0 verified)
    {
        dim3 grid(DMODEL / 64, ROWS / 64, 1);
        gemm_out_bf<<<grid, 256, 0, stream>>>(Abf, Wbf + 3ull * DMODEL * DMODEL, bo, out);
    }
}